// Round 6
// baseline (275.200 us; speedup 1.0000x reference)
//
#include <hip/hip_runtime.h>

// RGCN HighMem: out[dst[e]] += feat[src[e]] @ W[etypes[e]]
// E=200000, N=50000, R=64, D=32.
//
// Round 6: replace the 6.4M fp32 global-atomic scatter (measured-by-
// elimination as the ~25-30 us wall across rounds 1/4/5: ~250 G lane-ops/s)
// with a two-phase bucket sort:
//   prep(+dst-bucket hist) -> scan(782 buckets, 1 block) ->
//   msg (round-5 MFMA kernel; phase 1 claims pos = base[bucket]+cursor++,
//        phase 3 plain-STORES C fragments to msg[pos], dloc[pos]=d&63) ->
//   gather (1 block/bucket: coalesced stream of its contiguous msg rows,
//           ds_add_f32 into an 8KB LDS tile [64 nodes x 32], conflict-free
//           banks, single coalesced non-RMW write of out).
// d_ws is free (harness poisons it every iter regardless). out memset
// dropped: gather writes every output element (incl. deg-0 nodes -> 0).

#define D 32
#define NRELS 64
#define BLOCK 1024
#define WPB (BLOCK / 64)
#define GRID 256
#define MAXCHUNK 1024
#define MAXTILES (NRELS + MAXCHUNK / 16)
#define BUCKET 64            // nodes per dst bucket

typedef __bf16 bf16x8 __attribute__((ext_vector_type(8)));
typedef float  f32x4  __attribute__((ext_vector_type(4)));

static __device__ __forceinline__ unsigned int f2b(float x) {
    unsigned int u = __float_as_uint(x);
    return (u + 0x7fffu + ((u >> 16) & 1u)) >> 16;   // RNE bf16
}

// ---- prep: feat->bf16 rows; W->B-frag order; dst-bucket histogram ---------

__global__ __launch_bounds__(256) void prep_kernel(
    const float* __restrict__ feat, const float* __restrict__ weight,
    const int* __restrict__ dst,
    unsigned short* __restrict__ featb,   // [N*32] bf16
    unsigned short* __restrict__ wpack,   // [64][2][64][8] bf16
    int* __restrict__ hist,
    int n_nodes, int E)
{
    int idx = blockIdx.x * 256 + threadIdx.x;
    int nfeat = n_nodes * 4;                    // one task = 8 elements
    if (idx < nfeat) {
        const float4* fp = (const float4*)(feat + (size_t)idx * 8);
        float4 a = fp[0], b = fp[1];
        uint4 o;
        o.x = f2b(a.x) | (f2b(a.y) << 16);
        o.y = f2b(a.z) | (f2b(a.w) << 16);
        o.z = f2b(b.x) | (f2b(b.y) << 16);
        o.w = f2b(b.z) | (f2b(b.w) << 16);
        ((uint4*)featb)[idx] = o;
    } else if (idx < nfeat + NRELS * 2 * 64) {
        int t = idx - nfeat;
        int r = t >> 7, half = (t >> 6) & 1, lane = t & 63;
        int quad = lane >> 4, n = lane & 15;
        const float* W = weight + (size_t)r * (D * D) + half * 16 + n;
        uint4 o;
        unsigned int v[8];
        #pragma unroll
        for (int j = 0; j < 8; ++j) v[j] = f2b(W[(quad * 8 + j) * D]);
        o.x = v[0] | (v[1] << 16);
        o.y = v[2] | (v[3] << 16);
        o.z = v[4] | (v[5] << 16);
        o.w = v[6] | (v[7] << 16);
        ((uint4*)wpack)[t] = o;
    }
    if (idx < E) atomicAdd(&hist[dst[idx] >> 6], 1);
}

// ---- scan: exclusive scan of <=1023 bucket counts, one block --------------

__global__ __launch_bounds__(1024) void scan_kernel(
    const int* __restrict__ hist, int* __restrict__ base, int nb)
{
    __shared__ int wsum[16];
    int tid = threadIdx.x;
    int lane = tid & 63, wave = tid >> 6;
    int v = (tid < nb) ? hist[tid] : 0;
    int x = v;
    #pragma unroll
    for (int o = 1; o < 64; o <<= 1) {
        int y = __shfl_up(x, o, 64);
        if (lane >= o) x += y;
    }
    if (lane == 63) wsum[wave] = x;
    __syncthreads();
    if (wave == 0) {
        int s = (lane < 16) ? wsum[lane] : 0;
        #pragma unroll
        for (int o = 1; o < 16; o <<= 1) {
            int y = __shfl_up(s, o, 64);
            if (lane >= o) s += y;
        }
        if (lane < 16) wsum[lane] = s;     // inclusive wave sums
    }
    __syncthreads();
    int woff = (wave > 0) ? wsum[wave - 1] : 0;
    int excl = x + woff - v;
    if (tid <= nb) base[tid] = excl;       // base[nb] = E
}

// ---- msg: bucket-by-relation + MFMA + plain stores to sorted slots --------

__global__ __launch_bounds__(BLOCK, 4) void msg_kernel(
    const unsigned short* __restrict__ featb,
    const unsigned short* __restrict__ wpack,
    const int* __restrict__ src,
    const int* __restrict__ dst,
    const int* __restrict__ etypes,
    const int* __restrict__ base,
    int* __restrict__ cursor,
    float* __restrict__ msg,
    unsigned char* __restrict__ dloc,
    int E, int chunk)
{
    __shared__ int cnt[NRELS];
    __shared__ int off[NRELS];
    __shared__ unsigned short list[MAXCHUNK];
    __shared__ unsigned short desc[MAXTILES];
    __shared__ int ntile_sh;
    __shared__ int pos_sh[MAXCHUNK];

    int tid = threadIdx.x;
    int gbase = blockIdx.x * chunk;

    if (tid < NRELS) cnt[tid] = 0;
    __syncthreads();

    // phase 1: relation bucketing + claim dst-sorted slot
    int my_r = -1, my_rank = 0;
    if (tid < chunk && gbase + tid < E) {
        int e = gbase + tid;
        my_r = etypes[e];
        my_rank = atomicAdd(&cnt[my_r], 1);
        int d = dst[e];
        int b = d >> 6;
        int p = base[b] + atomicAdd(&cursor[b], 1);
        pos_sh[tid] = p;
        dloc[p] = (unsigned char)(d & (BUCKET - 1));
    }
    __syncthreads();

    // phase 2: wave 0 scans counts + builds relation-sorted tile descriptors
    if (tid < 64) {
        int c = cnt[tid];
        int x = c;
        #pragma unroll
        for (int o = 1; o < 64; o <<= 1) {
            int y = __shfl_up(x, o, 64);
            if (tid >= o) x += y;
        }
        off[tid] = x - c;

        int nt = (c + 15) >> 4;
        int tx = nt;
        #pragma unroll
        for (int o = 1; o < 64; o <<= 1) {
            int y = __shfl_up(tx, o, 64);
            if (tid >= o) tx += y;
        }
        int tbase = tx - nt;
        for (int t = 0; t < nt; ++t)
            desc[tbase + t] = (unsigned short)((tid << 8) | t);
        if (tid == 63) ntile_sh = tx;
    }
    __syncthreads();

    if (my_r >= 0) list[off[my_r] + my_rank] = (unsigned short)tid;
    int ntiles = ntile_sh;
    __syncthreads();

    // phase 3: MFMA tiles, store C fragments to sorted msg slots
    int wave = tid >> 6;
    int lane = tid & 63;
    int n    = lane & 15;
    int quad = lane >> 4;

    int per = (ntiles + WPB - 1) / WPB;
    int t0 = wave * per;
    int t1 = t0 + per; if (t1 > ntiles) t1 = ntiles;

    for (int ti = t0; ti < t1; ++ti) {
        int dsc = desc[ti];
        int r = dsc >> 8;
        int t = dsc & 255;
        int c = cnt[r];
        int mbase = t * 16;
        int mcnt = c - mbase; if (mcnt > 16) mcnt = 16;
        int lbase = off[r] + mbase;

        bf16x8 b0 = *(const bf16x8*)(wpack + ((size_t)(r * 2 + 0) * 64 + lane) * 8);
        bf16x8 b1 = *(const bf16x8*)(wpack + ((size_t)(r * 2 + 1) * 64 + lane) * 8);

        int mm = (n < mcnt) ? n : 0;
        int le = list[lbase + mm];
        int s  = src[gbase + le];
        bf16x8 a = *(const bf16x8*)(featb + (size_t)s * D + quad * 8);

        f32x4 z = {0.f, 0.f, 0.f, 0.f};
        f32x4 c0 = __builtin_amdgcn_mfma_f32_16x16x32_bf16(a, b0, z, 0, 0, 0);
        f32x4 c1 = __builtin_amdgcn_mfma_f32_16x16x32_bf16(a, b1, z, 0, 0, 0);

        // C: col = lane&15 (out col n), row = quad*4+v (edge in tile)
        #pragma unroll
        for (int v = 0; v < 4; ++v) {
            int m2 = quad * 4 + v;
            if (m2 < mcnt) {
                int p2 = pos_sh[list[lbase + m2]];
                msg[(size_t)p2 * D + n]      = c0[v];
                msg[(size_t)p2 * D + 16 + n] = c1[v];
            }
        }
    }
}

// ---- gather: per-bucket LDS accumulation, coalesced out write -------------

__global__ __launch_bounds__(512) void gather_kernel(
    const float* __restrict__ msg,
    const unsigned char* __restrict__ dloc,
    const int* __restrict__ base,
    float* __restrict__ out, int n_nodes)
{
    __shared__ float acc[BUCKET * D];     // 8 KB
    int b = blockIdx.x;
    int tid = threadIdx.x;
    for (int j = tid; j < BUCKET * D; j += 512) acc[j] = 0.f;
    __syncthreads();

    int e0 = base[b], e1 = base[b + 1];
    int g = tid >> 5, o = tid & 31;       // 16 groups of 32 lanes
    for (int i = e0 + g; i < e1; i += 16) {
        float m = msg[(size_t)i * D + o];           // 128B coalesced per group
        int dl = dloc[i];
        atomicAdd(&acc[dl * D + o], m);             // ds_add_f32, banks = o
    }
    __syncthreads();

    int node0 = b * BUCKET;
    int nn = n_nodes - node0; if (nn > BUCKET) nn = BUCKET;
    for (int j = tid; j < nn * D; j += 512)
        out[(size_t)node0 * D + j] = acc[j];
}

// ---- fallback (round-1 kernel) --------------------------------------------

__global__ __launch_bounds__(256) void rgcn_edge_kernel(
    const float* __restrict__ feat, const float* __restrict__ weight,
    const int* __restrict__ src, const int* __restrict__ dst,
    const int* __restrict__ etypes, float* __restrict__ out, int n_edges)
{
    int gid = blockIdx.x * blockDim.x + threadIdx.x;
    int e = gid >> 5;
    int o = gid & 31;
    if (e >= n_edges) return;
    int s = src[e], d = dst[e], r = etypes[e];
    const float* W = weight + (size_t)r * (D * D);
    float fv = feat[(size_t)s * D + o];
    float acc = 0.f;
    #pragma unroll
    for (int i = 0; i < D; ++i) {
        float fi = __shfl(fv, i, 32);
        acc = fmaf(fi, W[i * D + o], acc);
    }
    atomicAdd(&out[(size_t)d * D + o], acc);
}

// ---- launch ---------------------------------------------------------------

extern "C" void kernel_launch(void* const* d_in, const int* in_sizes, int n_in,
                              void* d_out, int out_size, void* d_ws, size_t ws_size,
                              hipStream_t stream) {
    const float* feat   = (const float*)d_in[0];
    const float* weight = (const float*)d_in[1];
    const int*   src    = (const int*)d_in[2];
    const int*   dst    = (const int*)d_in[3];
    const int*   etypes = (const int*)d_in[4];
    float*       out    = (float*)d_out;

    int N = in_sizes[0] / D;
    int R = in_sizes[1] / (D * D);
    int E = in_sizes[2];
    int NB = (N + BUCKET - 1) / BUCKET;
    int chunk = (E + GRID - 1) / GRID;

    // ws layout (bytes, all 16B-aligned by construction for our shape)
    size_t featb_off = 0;
    size_t featb_sz  = ((size_t)N * D * 2 + 15) & ~(size_t)15;
    size_t wpack_off = featb_off + featb_sz;
    size_t wpack_sz  = (size_t)NRELS * 2 * 64 * 8 * 2;
    size_t msg_off   = wpack_off + wpack_sz;
    size_t msg_sz    = (size_t)E * D * 4;
    size_t dloc_off  = msg_off + msg_sz;
    size_t dloc_sz   = ((size_t)E + 15) & ~(size_t)15;
    size_t hist_off  = dloc_off + dloc_sz;
    size_t hist_sz   = (size_t)NB * 4;
    size_t curs_off  = hist_off + hist_sz;
    size_t curs_sz   = (size_t)NB * 4;
    size_t base_off  = curs_off + curs_sz;
    size_t base_sz   = (size_t)(NB + 1) * 4;
    size_t need      = base_off + base_sz;

    if (R != NRELS || chunk > MAXCHUNK || NB + 1 > 1024 || ws_size < need) {
        hipMemsetAsync(d_out, 0, (size_t)out_size * sizeof(float), stream);
        long long total = (long long)E * 32;
        int grid = (int)((total + 255) / 256);
        rgcn_edge_kernel<<<grid, 256, 0, stream>>>(feat, weight, src, dst,
                                                   etypes, out, E);
        return;
    }

    char* ws = (char*)d_ws;
    unsigned short* featb = (unsigned short*)(ws + featb_off);
    unsigned short* wpack = (unsigned short*)(ws + wpack_off);
    float*          msg   = (float*)(ws + msg_off);
    unsigned char*  dloc  = (unsigned char*)(ws + dloc_off);
    int*            hist  = (int*)(ws + hist_off);
    int*            curs  = (int*)(ws + curs_off);
    int*            basep = (int*)(ws + base_off);

    // zero hist + cursor (contiguous)
    hipMemsetAsync(hist, 0, hist_sz + curs_sz, stream);

    int nfeat = N * 4;
    int prep_tasks = nfeat + NRELS * 2 * 64;
    if (prep_tasks < E) prep_tasks = E;
    prep_kernel<<<(prep_tasks + 255) / 256, 256, 0, stream>>>(
        feat, weight, dst, featb, wpack, hist, N, E);

    scan_kernel<<<1, 1024, 0, stream>>>(hist, basep, NB);

    msg_kernel<<<GRID, BLOCK, 0, stream>>>(featb, wpack, src, dst, etypes,
                                           basep, curs, msg, dloc, E, chunk);

    gather_kernel<<<NB, 512, 0, stream>>>(msg, dloc, basep, out, N);
}

// Round 7
// 134.062 us; speedup vs baseline: 2.0528x; 2.0528x over previous
//
#include <hip/hip_runtime.h>

// RGCN HighMem: out[dst[e]] += feat[src[e]] @ W[etypes[e]]
// E=200000, N=50000, R=64, D=32.
//
// Round 7: two-phase (relation-tiled MFMA msg -> bucket gather) with a
// FULLY DETERMINISTIC counting sort by dst-bucket. Round 6 died on 200k
// *returning* device atomics over 782 cursors (256-deep same-address
// serialization + block barrier => msg_kernel 117 us @ 1.3% VALUBusy).
// Here slot = base[bucket] + histT_prefix[block][bucket] + LDS-local rank;
// the only atomics left are LDS (trivial) and none are device-scope.
//   prep : featb bf16 pack, wpack B-frag pack, per-block dst-bucket LDS
//          histogram -> histT[block][bucket]  (coalesced row write)
//   scanA: 782 blocks (1 wave): exclusive scan histT column in-place + total
//   scanB: 1 block: exclusive scan of 782 totals -> base[], base[NB]=E
//   msg  : round-6 MFMA kernel; phase 1 rank via LDS counters preloaded
//          with base+prefix; plain scatter stores of C to msg[p]
//   gather: per bucket, contiguous coalesced msg read, LDS fp32 adds,
//          coalesced out write (exact fp32; writes every element, no memset)

#define D 32
#define NRELS 64
#define BLOCK 1024
#define WPB (BLOCK / 64)
#define NBLK 256             // msg/prep chunk blocks (must stay 256: scanA)
#define MAXCHUNK 1024
#define MAXTILES (NRELS + MAXCHUNK / 16)
#define BUCKET 64            // nodes per dst bucket
#define MAXNB 1023           // scanB limit

typedef __bf16 bf16x8 __attribute__((ext_vector_type(8)));
typedef float  f32x4  __attribute__((ext_vector_type(4)));

static __device__ __forceinline__ unsigned int f2b(float x) {
    unsigned int u = __float_as_uint(x);
    return (u + 0x7fffu + ((u >> 16) & 1u)) >> 16;   // RNE bf16
}

// ---- prep: packs + per-block dst-bucket histogram -------------------------

__global__ __launch_bounds__(BLOCK) void prep_kernel(
    const float* __restrict__ feat, const float* __restrict__ weight,
    const int* __restrict__ dst,
    unsigned short* __restrict__ featb,   // [N*32] bf16
    unsigned short* __restrict__ wpack,   // [64][2][64][8] bf16
    int* __restrict__ histT,              // [NBLK][NB]
    int n_nodes, int E, int nb, int chunk)
{
    __shared__ int lh[MAXNB];
    int tid = threadIdx.x;
    int idx = blockIdx.x * BLOCK + tid;

    // phase A: pack tasks (one shot; grid covers nfeat + 8192 tasks)
    int nfeat = n_nodes * 4;                    // one task = 8 elements
    if (idx < nfeat) {
        const float4* fp = (const float4*)(feat + (size_t)idx * 8);
        float4 a = fp[0], b = fp[1];
        uint4 o;
        o.x = f2b(a.x) | (f2b(a.y) << 16);
        o.y = f2b(a.z) | (f2b(a.w) << 16);
        o.z = f2b(b.x) | (f2b(b.y) << 16);
        o.w = f2b(b.z) | (f2b(b.w) << 16);
        ((uint4*)featb)[idx] = o;
    } else if (idx < nfeat + NRELS * 2 * 64) {
        int t = idx - nfeat;
        int r = t >> 7, half = (t >> 6) & 1, lane = t & 63;
        int quad = lane >> 4, n = lane & 15;
        const float* W = weight + (size_t)r * (D * D) + half * 16 + n;
        uint4 o;
        unsigned int v[8];
        #pragma unroll
        for (int j = 0; j < 8; ++j) v[j] = f2b(W[(quad * 8 + j) * D]);
        o.x = v[0] | (v[1] << 16);
        o.y = v[2] | (v[3] << 16);
        o.z = v[4] | (v[5] << 16);
        o.w = v[6] | (v[7] << 16);
        ((uint4*)wpack)[t] = o;
    }

    // phase B: this block's edge-chunk histogram over dst buckets
    for (int k = tid; k < nb; k += BLOCK) lh[k] = 0;
    __syncthreads();
    int gbase = blockIdx.x * chunk;
    if (tid < chunk && gbase + tid < E)
        atomicAdd(&lh[dst[gbase + tid] >> 6], 1);
    __syncthreads();
    int* row = histT + (size_t)blockIdx.x * nb;
    for (int k = tid; k < nb; k += BLOCK) row[k] = lh[k];
}

// ---- scanA: per bucket, exclusive scan over the 256 block counts ----------

__global__ __launch_bounds__(64) void scanA_kernel(
    int* __restrict__ histT, int* __restrict__ total, int nb)
{
    int k = blockIdx.x;           // bucket
    int lane = threadIdx.x;       // 0..63, each owns 4 block slots
    int v[4];
    #pragma unroll
    for (int j = 0; j < 4; ++j)
        v[j] = histT[(size_t)(lane * 4 + j) * nb + k];
    int lsum = v[0] + v[1] + v[2] + v[3];
    int x = lsum;
    #pragma unroll
    for (int o = 1; o < 64; o <<= 1) {
        int y = __shfl_up(x, o, 64);
        if (lane >= o) x += y;
    }
    int run = x - lsum;           // exclusive prefix of this lane's group
    #pragma unroll
    for (int j = 0; j < 4; ++j) {
        histT[(size_t)(lane * 4 + j) * nb + k] = run;
        run += v[j];
    }
    if (lane == 63) total[k] = x;
}

// ---- scanB: exclusive scan of bucket totals (nb <= 1023), one block -------

__global__ __launch_bounds__(1024) void scanB_kernel(
    const int* __restrict__ total, int* __restrict__ base, int nb)
{
    __shared__ int wsum[16];
    int tid = threadIdx.x;
    int lane = tid & 63, wave = tid >> 6;
    int v = (tid < nb) ? total[tid] : 0;
    int x = v;
    #pragma unroll
    for (int o = 1; o < 64; o <<= 1) {
        int y = __shfl_up(x, o, 64);
        if (lane >= o) x += y;
    }
    if (lane == 63) wsum[wave] = x;
    __syncthreads();
    if (wave == 0) {
        int s = (lane < 16) ? wsum[lane] : 0;
        #pragma unroll
        for (int o = 1; o < 16; o <<= 1) {
            int y = __shfl_up(s, o, 64);
            if (lane >= o) s += y;
        }
        if (lane < 16) wsum[lane] = s;
    }
    __syncthreads();
    int woff = (wave > 0) ? wsum[wave - 1] : 0;
    if (tid <= nb) base[tid] = x + woff - v;   // exclusive; base[nb] = E
}

// ---- msg: relation-tiled MFMA + deterministic scatter stores --------------

__global__ __launch_bounds__(BLOCK, 4) void msg_kernel(
    const unsigned short* __restrict__ featb,
    const unsigned short* __restrict__ wpack,
    const int* __restrict__ src,
    const int* __restrict__ dst,
    const int* __restrict__ etypes,
    const int* __restrict__ base,
    const int* __restrict__ histT,
    float* __restrict__ msg,
    unsigned char* __restrict__ dloc,
    int E, int chunk, int nb)
{
    __shared__ int cnt[NRELS];
    __shared__ int off[NRELS];
    __shared__ unsigned short list[MAXCHUNK];
    __shared__ unsigned short desc[MAXTILES];
    __shared__ int ntile_sh;
    __shared__ int pos_sh[MAXCHUNK];
    __shared__ int lcnt[MAXNB];

    int tid = threadIdx.x;
    int gbase = blockIdx.x * chunk;

    // phase 0: preload slot counters = global base + this block's prefix
    const int* row = histT + (size_t)blockIdx.x * nb;
    for (int k = tid; k < nb; k += BLOCK) lcnt[k] = base[k] + row[k];
    if (tid < NRELS) cnt[tid] = 0;
    __syncthreads();

    // phase 1: relation bucketing + deterministic dst-sorted slot (LDS only)
    int my_r = -1, my_rank = 0;
    if (tid < chunk && gbase + tid < E) {
        int e = gbase + tid;
        my_r = etypes[e];
        my_rank = atomicAdd(&cnt[my_r], 1);
        int d = dst[e];
        int p = atomicAdd(&lcnt[d >> 6], 1);
        pos_sh[tid] = p;
        dloc[p] = (unsigned char)(d & (BUCKET - 1));
    }
    __syncthreads();

    // phase 2: wave 0 scans counts + builds relation-sorted tile descriptors
    if (tid < 64) {
        int c = cnt[tid];
        int x = c;
        #pragma unroll
        for (int o = 1; o < 64; o <<= 1) {
            int y = __shfl_up(x, o, 64);
            if (tid >= o) x += y;
        }
        off[tid] = x - c;

        int nt = (c + 15) >> 4;
        int tx = nt;
        #pragma unroll
        for (int o = 1; o < 64; o <<= 1) {
            int y = __shfl_up(tx, o, 64);
            if (tid >= o) tx += y;
        }
        int tbase = tx - nt;
        for (int t = 0; t < nt; ++t)
            desc[tbase + t] = (unsigned short)((tid << 8) | t);
        if (tid == 63) ntile_sh = tx;
    }
    __syncthreads();

    if (my_r >= 0) list[off[my_r] + my_rank] = (unsigned short)tid;
    int ntiles = ntile_sh;
    __syncthreads();

    // phase 3: MFMA tiles, plain stores of C fragments to sorted msg slots
    int wave = tid >> 6;
    int lane = tid & 63;
    int n    = lane & 15;
    int quad = lane >> 4;

    int per = (ntiles + WPB - 1) / WPB;
    int t0 = wave * per;
    int t1 = t0 + per; if (t1 > ntiles) t1 = ntiles;

    for (int ti = t0; ti < t1; ++ti) {
        int dsc = desc[ti];
        int r = dsc >> 8;
        int t = dsc & 255;
        int c = cnt[r];
        int mbase = t * 16;
        int mcnt = c - mbase; if (mcnt > 16) mcnt = 16;
        int lbase = off[r] + mbase;

        bf16x8 b0 = *(const bf16x8*)(wpack + ((size_t)(r * 2 + 0) * 64 + lane) * 8);
        bf16x8 b1 = *(const bf16x8*)(wpack + ((size_t)(r * 2 + 1) * 64 + lane) * 8);

        int mm = (n < mcnt) ? n : 0;
        int le = list[lbase + mm];
        int s  = src[gbase + le];
        bf16x8 a = *(const bf16x8*)(featb + (size_t)s * D + quad * 8);

        f32x4 z = {0.f, 0.f, 0.f, 0.f};
        f32x4 c0 = __builtin_amdgcn_mfma_f32_16x16x32_bf16(a, b0, z, 0, 0, 0);
        f32x4 c1 = __builtin_amdgcn_mfma_f32_16x16x32_bf16(a, b1, z, 0, 0, 0);

        // C: col = lane&15 (out col n), row = quad*4+v (edge in tile)
        #pragma unroll
        for (int v = 0; v < 4; ++v) {
            int m2 = quad * 4 + v;
            if (m2 < mcnt) {
                int p2 = pos_sh[list[lbase + m2]];
                msg[(size_t)p2 * D + n]      = c0[v];
                msg[(size_t)p2 * D + 16 + n] = c1[v];
            }
        }
    }
}

// ---- gather: per-bucket LDS accumulation, coalesced out write -------------

__global__ __launch_bounds__(512) void gather_kernel(
    const float* __restrict__ msg,
    const unsigned char* __restrict__ dloc,
    const int* __restrict__ base,
    float* __restrict__ out, int n_nodes)
{
    __shared__ float acc[BUCKET * D];     // 8 KB
    int b = blockIdx.x;
    int tid = threadIdx.x;
    for (int j = tid; j < BUCKET * D; j += 512) acc[j] = 0.f;
    __syncthreads();

    int e0 = base[b], e1 = base[b + 1];
    int g = tid >> 5, o = tid & 31;       // 16 groups of 32 lanes
    for (int i = e0 + g; i < e1; i += 16) {
        float m = msg[(size_t)i * D + o];           // contiguous, coalesced
        int dl = dloc[i];
        atomicAdd(&acc[dl * D + o], m);             // LDS fp32 add, banks = o
    }
    __syncthreads();

    int node0 = b * BUCKET;
    int nn = n_nodes - node0; if (nn > BUCKET) nn = BUCKET;
    for (int j = tid; j < nn * D; j += 512)
        out[(size_t)node0 * D + j] = acc[j];
}

// ---- fallback (round-1 kernel) --------------------------------------------

__global__ __launch_bounds__(256) void rgcn_edge_kernel(
    const float* __restrict__ feat, const float* __restrict__ weight,
    const int* __restrict__ src, const int* __restrict__ dst,
    const int* __restrict__ etypes, float* __restrict__ out, int n_edges)
{
    int gid = blockIdx.x * blockDim.x + threadIdx.x;
    int e = gid >> 5;
    int o = gid & 31;
    if (e >= n_edges) return;
    int s = src[e], d = dst[e], r = etypes[e];
    const float* W = weight + (size_t)r * (D * D);
    float fv = feat[(size_t)s * D + o];
    float acc = 0.f;
    #pragma unroll
    for (int i = 0; i < D; ++i) {
        float fi = __shfl(fv, i, 32);
        acc = fmaf(fi, W[i * D + o], acc);
    }
    atomicAdd(&out[(size_t)d * D + o], acc);
}

// ---- launch ---------------------------------------------------------------

extern "C" void kernel_launch(void* const* d_in, const int* in_sizes, int n_in,
                              void* d_out, int out_size, void* d_ws, size_t ws_size,
                              hipStream_t stream) {
    const float* feat   = (const float*)d_in[0];
    const float* weight = (const float*)d_in[1];
    const int*   src    = (const int*)d_in[2];
    const int*   dst    = (const int*)d_in[3];
    const int*   etypes = (const int*)d_in[4];
    float*       out    = (float*)d_out;

    int N = in_sizes[0] / D;
    int R = in_sizes[1] / (D * D);
    int E = in_sizes[2];
    int NB = (N + BUCKET - 1) / BUCKET;           // 782
    int chunk = (E + NBLK - 1) / NBLK;            // 782
    int nfeat = N * 4;

    // ws layout (bytes; all 16B-aligned by construction)
    size_t featb_off = 0;
    size_t featb_sz  = ((size_t)N * D * 2 + 15) & ~(size_t)15;
    size_t wpack_off = featb_off + featb_sz;
    size_t wpack_sz  = (size_t)NRELS * 2 * 64 * 8 * 2;
    size_t msg_off   = wpack_off + wpack_sz;
    size_t msg_sz    = (size_t)E * D * 4;
    size_t dloc_off  = msg_off + msg_sz;
    size_t dloc_sz   = ((size_t)E + 15) & ~(size_t)15;
    size_t hist_off  = dloc_off + dloc_sz;
    size_t hist_sz   = ((size_t)NBLK * NB * 4 + 15) & ~(size_t)15;
    size_t tot_off   = hist_off + hist_sz;
    size_t tot_sz    = ((size_t)NB * 4 + 15) & ~(size_t)15;
    size_t base_off  = tot_off + tot_sz;
    size_t base_sz   = (size_t)(NB + 1) * 4;
    size_t need      = base_off + base_sz;

    bool ok = (R == NRELS) && (chunk <= MAXCHUNK) && (NB <= MAXNB)
           && (nfeat + NRELS * 2 * 64 <= NBLK * BLOCK) && (ws_size >= need);

    if (!ok) {
        hipMemsetAsync(d_out, 0, (size_t)out_size * sizeof(float), stream);
        long long total = (long long)E * 32;
        int grid = (int)((total + 255) / 256);
        rgcn_edge_kernel<<<grid, 256, 0, stream>>>(feat, weight, src, dst,
                                                   etypes, out, E);
        return;
    }

    char* ws = (char*)d_ws;
    unsigned short* featb = (unsigned short*)(ws + featb_off);
    unsigned short* wpack = (unsigned short*)(ws + wpack_off);
    float*          msg   = (float*)(ws + msg_off);
    unsigned char*  dloc  = (unsigned char*)(ws + dloc_off);
    int*            histT = (int*)(ws + hist_off);
    int*            totp  = (int*)(ws + tot_off);
    int*            basep = (int*)(ws + base_off);

    prep_kernel<<<NBLK, BLOCK, 0, stream>>>(feat, weight, dst, featb, wpack,
                                            histT, N, E, NB, chunk);
    scanA_kernel<<<NB, 64, 0, stream>>>(histT, totp, NB);
    scanB_kernel<<<1, 1024, 0, stream>>>(totp, basep, NB);
    msg_kernel<<<NBLK, BLOCK, 0, stream>>>(featb, wpack, src, dst, etypes,
                                           basep, histT, msg, dloc,
                                           E, chunk, NB);
    gather_kernel<<<NB, 512, 0, stream>>>(msg, dloc, basep, out, N);
}